// Round 1
// baseline (669.610 us; speedup 1.0000x reference)
//
#include <hip/hip_runtime.h>
#include <hip/hip_bf16.h>

#define Bsz 256
#define NIM 36   // im rows after slice [1:]
#define NS  32   // s rows after slice [1:-2]
#define KD  1024

typedef __attribute__((ext_vector_type(8))) short  bf16x8;
typedef __attribute__((ext_vector_type(4))) float  f32x4;
typedef __attribute__((ext_vector_type(8))) unsigned short ushort8;

static __device__ __forceinline__ unsigned short f2bf(float f) {
  unsigned u = __builtin_bit_cast(unsigned, f);
  u += 0x7fffu + ((u >> 16) & 1u);
  return (unsigned short)(u >> 16);
}

// Kernel 1: convert f32 -> bf16, apply slicing and length masks (zero invalid rows).
__global__ void stage_kernel(const float* __restrict__ im_set,
                             const float* __restrict__ s_seq,
                             const int* __restrict__ im_len,
                             const int* __restrict__ s_len,
                             unsigned short* __restrict__ im_bf,
                             unsigned short* __restrict__ s_bf) {
  const int IM_CHUNKS = Bsz * NIM * KD / 8;  // 1179648
  const int S_CHUNKS  = Bsz * NS  * KD / 8;  // 1048576
  int idx = blockIdx.x * blockDim.x + threadIdx.x;
  if (idx < IM_CHUNKS) {
    int flat = idx * 8;
    int i   = flat / (NIM * KD);
    int rem = flat - i * (NIM * KD);
    int n   = rem / KD;
    int k   = rem - n * KD;
    bool valid = n < (im_len[i] - 1);
    ushort8 o;
    if (valid) {
      const float* src = im_set + ((size_t)i * 37 + n + 1) * KD + k;
      #pragma unroll
      for (int t = 0; t < 8; ++t) o[t] = f2bf(src[t]);
    } else {
      #pragma unroll
      for (int t = 0; t < 8; ++t) o[t] = 0;
    }
    *(ushort8*)(im_bf + flat) = o;
  } else if (idx < IM_CHUNKS + S_CHUNKS) {
    int flat = (idx - IM_CHUNKS) * 8;
    int j   = flat / (NS * KD);
    int rem = flat - j * (NS * KD);
    int m   = rem / KD;
    int k   = rem - m * KD;
    bool valid = m < (s_len[j] - 3);
    ushort8 o;
    if (valid) {
      const float* src = s_seq + ((size_t)j * 35 + m + 1) * KD + k;
      #pragma unroll
      for (int t = 0; t < 8; ++t) o[t] = f2bf(src[t]);
    } else {
      #pragma unroll
      for (int t = 0; t < 8; ++t) o[t] = 0;
    }
    *(ushort8*)(s_bf + flat) = o;
  }
}

// Kernel 2: per-pair scores. Each wave: 1 i x 4 j's. Block: 4 waves (i-group of 4, shared j-group).
__global__ __launch_bounds__(256) void score_kernel(const unsigned short* __restrict__ im_bf,
                                                    const unsigned short* __restrict__ s_bf,
                                                    float* __restrict__ scores) {
  const int lane = threadIdx.x & 63;
  const int wave = threadIdx.x >> 6;
  const int ig = blockIdx.x >> 6;   // 64 i-groups
  const int jg = blockIdx.x & 63;   // 64 j-groups (varies fastest -> im stays L2-hot)
  const int i  = ig * 4 + wave;
  const int j0 = jg * 4;
  const int l15 = lane & 15;
  const int khi = (lane >> 4) * 8;

  const unsigned short* Ab = im_bf + (size_t)i  * NIM * KD;
  const unsigned short* Bb = s_bf  + (size_t)j0 * NS  * KD;

  f32x4 acc[4][3][2] = {};   // [q][mt][nt]

  for (int kk = 0; kk < KD; kk += 32) {
    bf16x8 a[3];
    #pragma unroll
    for (int mt = 0; mt < 3; ++mt) {
      int row = mt * 16 + l15;
      if (row < NIM)
        a[mt] = *(const bf16x8*)(Ab + row * KD + kk + khi);
      else
        a[mt] = (bf16x8)0;   // pad rows 36..47 -> zero dots
    }
    #pragma unroll
    for (int q = 0; q < 4; ++q) {
      #pragma unroll
      for (int nt = 0; nt < 2; ++nt) {
        bf16x8 b = *(const bf16x8*)(Bb + ((size_t)q * NS + nt * 16 + l15) * KD + kk + khi);
        #pragma unroll
        for (int mt = 0; mt < 3; ++mt)
          acc[q][mt][nt] = __builtin_amdgcn_mfma_f32_16x16x32_bf16(a[mt], b, acc[q][mt][nt], 0, 0, 0);
      }
    }
  }

  // Reduction: per column m (= nt*16 + l15): max over all 48 rows, then sum over the 32 columns.
  // Lane holds rows {mt*16 + (lane>>4)*4 + r}; cross-lane max over lanes sharing l15 via xor 16,32.
  #pragma unroll
  for (int q = 0; q < 4; ++q) {
    float cm[2];
    #pragma unroll
    for (int nt = 0; nt < 2; ++nt) {
      float m0 = -3.0e38f;
      #pragma unroll
      for (int mt = 0; mt < 3; ++mt)
        #pragma unroll
        for (int r = 0; r < 4; ++r)
          m0 = fmaxf(m0, acc[q][mt][nt][r]);
      m0 = fmaxf(m0, __shfl_xor(m0, 16));
      m0 = fmaxf(m0, __shfl_xor(m0, 32));
      cm[nt] = m0;
    }
    float sv = cm[0] + cm[1];
    sv += __shfl_xor(sv, 1);
    sv += __shfl_xor(sv, 2);
    sv += __shfl_xor(sv, 4);
    sv += __shfl_xor(sv, 8);
    if (lane == 0) scores[i * Bsz + j0 + q] = sv;
  }
}

// Kernel 3: contrastive-loss epilogue over the 256x256 score matrix.
__global__ void finalize_kernel(const float* __restrict__ scores, float* __restrict__ out) {
  __shared__ float diag[Bsz];
  __shared__ float wred[4];
  int t = threadIdx.x;
  diag[t] = scores[t * Bsz + t];
  __syncthreads();
  float di = diag[t];
  float mxs = 0.f, mxi = 0.f;  // costs are clamped >= 0 and diagonal forced 0
  for (int j = 0; j < Bsz; ++j) {
    if (j == t) continue;
    float srow = scores[t * Bsz + j];
    float scol = scores[j * Bsz + t];
    mxs = fmaxf(mxs, 0.2f + srow - di);  // cost_s row-max for i=t
    mxi = fmaxf(mxi, 0.2f + scol - di);  // cost_im col-max for j=t
  }
  float v = mxs + mxi;
  #pragma unroll
  for (int m = 32; m; m >>= 1) v += __shfl_xor(v, m);
  if ((t & 63) == 0) wred[t >> 6] = v;
  __syncthreads();
  if (t == 0) out[0] = wred[0] + wred[1] + wred[2] + wred[3];
}

extern "C" void kernel_launch(void* const* d_in, const int* in_sizes, int n_in,
                              void* d_out, int out_size, void* d_ws, size_t ws_size,
                              hipStream_t stream) {
  const float* im_set = (const float*)d_in[0];
  const float* s_seq  = (const float*)d_in[1];
  const int*   im_len = (const int*)d_in[2];
  const int*   s_len  = (const int*)d_in[3];
  float* out = (float*)d_out;

  unsigned short* im_bf = (unsigned short*)d_ws;                       // 256*36*1024*2 = 18,874,368 B
  unsigned short* s_bf  = im_bf + (size_t)Bsz * NIM * KD;              // 256*32*1024*2 = 16,777,216 B
  float* scores = (float*)(s_bf + (size_t)Bsz * NS * KD);              // 256*256*4     =    262,144 B

  const int total_chunks = Bsz * NIM * KD / 8 + Bsz * NS * KD / 8;     // 2,228,224
  stage_kernel<<<(total_chunks + 255) / 256, 256, 0, stream>>>(
      im_set, s_seq, im_len, s_len, im_bf, s_bf);

  score_kernel<<<64 * 64, 256, 0, stream>>>(im_bf, s_bf, scores);

  finalize_kernel<<<1, Bsz, 0, stream>>>(scores, out);
}

// Round 2
// 211.907 us; speedup vs baseline: 3.1599x; 3.1599x over previous
//
#include <hip/hip_runtime.h>
#include <hip/hip_bf16.h>

#define Bsz 256
#define NIM 36   // im rows after slice [1:]
#define NS  32   // s rows after slice [1:-2]
#define KD  1024

typedef __attribute__((ext_vector_type(8))) short  bf16x8;
typedef __attribute__((ext_vector_type(4))) float  f32x4;
typedef __attribute__((ext_vector_type(8))) unsigned short ushort8;

static __device__ __forceinline__ unsigned short f2bf(float f) {
  unsigned u = __builtin_bit_cast(unsigned, f);
  u += 0x7fffu + ((u >> 16) & 1u);
  return (unsigned short)(u >> 16);
}

static __device__ __forceinline__ void gload_lds16(const void* g, void* l) {
  __builtin_amdgcn_global_load_lds(
      (const __attribute__((address_space(1))) unsigned int*)g,
      (__attribute__((address_space(3))) unsigned int*)l, 16, 0, 0);
}

// ---------------- stage: f32 -> bf16, slicing + length masks, no int division ----------------
__global__ void stage_im(const float* __restrict__ im_set, const int* __restrict__ im_len,
                         unsigned short* __restrict__ im_bf) {
  int i = blockIdx.y;
  int chunk = blockIdx.x * 256 + threadIdx.x;   // 18*256 = 4608 chunks = 36*1024/8
  int n = chunk >> 7;
  int k = (chunk & 127) << 3;
  bool valid = n < (im_len[i] - 1);
  ushort8 o;
  if (valid) {
    const float* src = im_set + ((size_t)i * 37 + n + 1) * KD + k;
    #pragma unroll
    for (int t = 0; t < 8; ++t) o[t] = f2bf(src[t]);
  } else {
    #pragma unroll
    for (int t = 0; t < 8; ++t) o[t] = 0;
  }
  *(ushort8*)(im_bf + ((size_t)i * NIM + n) * KD + k) = o;
}

__global__ void stage_s(const float* __restrict__ s_seq, const int* __restrict__ s_len,
                        unsigned short* __restrict__ s_bf) {
  int j = blockIdx.y;
  int chunk = blockIdx.x * 256 + threadIdx.x;   // 16*256 = 4096 chunks = 32*1024/8
  int m = chunk >> 7;
  int k = (chunk & 127) << 3;
  bool valid = m < (s_len[j] - 3);
  ushort8 o;
  if (valid) {
    const float* src = s_seq + ((size_t)j * 35 + m + 1) * KD + k;
    #pragma unroll
    for (int t = 0; t < 8; ++t) o[t] = f2bf(src[t]);
  } else {
    #pragma unroll
    for (int t = 0; t < 8; ++t) o[t] = 0;
  }
  *(ushort8*)(s_bf + ((size_t)j * NS + m) * KD + k) = o;
}

// ---------------- score: BM=144 (4 pairs) x BN=256 (8 j), BK=32, LDS double-buffered ----------------
// LDS layout per buffer (25600 B): A [144 rows][64 B], then B [256 rows][64 B] at +9216.
// Granule swizzle: 16B granule g of row r lives at slot g ^ ((r>>1)&3)  (both sides: staged source
// address is inverse-permuted; ds_read applies the same XOR). 2-way bank access -> free.
__global__ __launch_bounds__(256, 2) void score_kernel(const unsigned short* __restrict__ im_bf,
                                                       const unsigned short* __restrict__ s_bf,
                                                       float* __restrict__ scores) {
  __shared__ __align__(16) unsigned char smem[2 * 25600];
  const int tid  = threadIdx.x;
  const int lane = tid & 63;
  const int w    = tid >> 6;          // wave 0..3, owns cols w*64..w*64+63
  const int l15  = lane & 15;
  const int q    = (lane >> 4) & 3;

  // XCD-aware mapping: XCD x owns ig in [x*8, x*8+8) (A-stripe 2.3MB, L2-resident),
  // ig varies fastest so the 8 igs reuse each B tile.
  int bid = blockIdx.x;
  int x = bid & 7, t = bid >> 3;
  int ig = x * 8 + (t & 7);           // 0..63
  int jg = t >> 3;                    // 0..31
  const int i0    = ig * 4;           // 4 images (144 rows)
  const int j0    = jg * 8;           // 8 sentences (256 rows)

  // staging chunk assignment: 25 chunks of 1024 B (A:0..8, B:9..24), wave w takes ch = w+4s
  const unsigned short* gbase[7];
  int ldsoff[7];
  {
    const int lrow4 = lane >> 2;      // 0..15 rows within chunk
    const int g     = lane & 3;       // linear granule slot
    #pragma unroll
    for (int s = 0; s < 7; ++s) {
      int ch = w + 4 * s;
      if (ch < 25) {
        if (ch < 9) {
          int r  = ch * 16 + lrow4;               // 0..143
          int gd = g ^ ((r >> 1) & 3);            // source granule for this slot
          int il = r / 36;
          int n  = r - il * 36;
          gbase[s] = im_bf + (((size_t)(i0 + il) * NIM + n) << 10) + gd * 8;
          ldsoff[s] = ch * 1024;
        } else {
          int rb = (ch - 9) * 16 + lrow4;         // 0..255
          int gd = g ^ ((rb >> 1) & 3);
          int jl = rb >> 5, m = rb & 31;
          gbase[s] = s_bf + (((size_t)(j0 + jl) * NS + m) << 10) + gd * 8;
          ldsoff[s] = 9216 + (ch - 9) * 1024;
        }
      }
    }
  }

  f32x4 acc[9][4] = {};
  // per-lane read bases: frag element (row = tile*16 + l15, kgranule = q), swizzled
  const int sw   = (q ^ ((l15 >> 1) & 3)) * 16;
  const int aoff = l15 * 64 + sw;                  // + mt*1024
  const int boff = 9216 + w * 4096 + l15 * 64 + sw; // + nt*1024

  // prologue: stage k-tile 0 into buffer 0
  #pragma unroll
  for (int s = 0; s < 7; ++s) {
    int ch = w + 4 * s;
    if (ch < 25) gload_lds16(gbase[s], smem + ldsoff[s]);
  }
  __syncthreads();

  for (int kt = 0; kt < 32; ++kt) {
    const int cur = kt & 1;
    if (kt < 31) {
      const int bo = (cur ^ 1) * 25600;
      const int kbyte = (kt + 1) * 64;
      #pragma unroll
      for (int s = 0; s < 7; ++s) {
        int ch = w + 4 * s;
        if (ch < 25) gload_lds16((const unsigned char*)gbase[s] + kbyte, smem + bo + ldsoff[s]);
      }
    }
    const unsigned char* base = smem + cur * 25600;
    bf16x8 a[9];
    #pragma unroll
    for (int mt = 0; mt < 9; ++mt)
      a[mt] = *(const bf16x8*)(base + aoff + mt * 1024);
    #pragma unroll
    for (int nt = 0; nt < 4; ++nt) {
      bf16x8 b = *(const bf16x8*)(base + boff + nt * 1024);
      #pragma unroll
      for (int mt = 0; mt < 9; ++mt)
        acc[mt][nt] = __builtin_amdgcn_mfma_f32_16x16x32_bf16(a[mt], b, acc[mt][nt], 0, 0, 0);
    }
    __syncthreads();   // drains own vmcnt (stage done) + lgkm, then barrier
  }

  // ---- epilogue: per-pair (36-row) column max, then sum over each j's 32 cols ----
  // acc value at (row = mt*16 + q*4 + r, col = w*64 + nt*16 + l15)
  float cmax[4][4];
  #pragma unroll
  for (int p = 0; p < 4; ++p)
    #pragma unroll
    for (int nt = 0; nt < 4; ++nt) cmax[p][nt] = -3.0e38f;

  #pragma unroll
  for (int mt = 0; mt < 9; ++mt) {
    #pragma unroll
    for (int r = 0; r < 4; ++r) {
      const int row = mt * 16 + q * 4 + r;
      #pragma unroll
      for (int p = 0; p < 4; ++p) {
        if (mt * 16 + r + 12 >= 36 * p && mt * 16 + r < 36 * (p + 1)) {  // compile-time prune
          bool in = (row >= 36 * p) && (row < 36 * p + 36);
          #pragma unroll
          for (int nt = 0; nt < 4; ++nt)
            cmax[p][nt] = in ? fmaxf(cmax[p][nt], acc[mt][nt][r]) : cmax[p][nt];
        }
      }
    }
  }
  #pragma unroll
  for (int p = 0; p < 4; ++p)
    #pragma unroll
    for (int nt = 0; nt < 4; ++nt) {
      float m0 = cmax[p][nt];
      m0 = fmaxf(m0, __shfl_xor(m0, 16));
      m0 = fmaxf(m0, __shfl_xor(m0, 32));
      cmax[p][nt] = m0;
    }
  #pragma unroll
  for (int p = 0; p < 4; ++p) {
    #pragma unroll
    for (int h = 0; h < 2; ++h) {
      float sv = cmax[p][2 * h] + cmax[p][2 * h + 1];
      sv += __shfl_xor(sv, 1);
      sv += __shfl_xor(sv, 2);
      sv += __shfl_xor(sv, 4);
      sv += __shfl_xor(sv, 8);
      if (lane == 0) scores[(i0 + p) * Bsz + (j0 + w * 2 + h)] = sv;
    }
  }
}

// ---------------- finalize: contrastive loss over 256x256 scores ----------------
__global__ void finalize_kernel(const float* __restrict__ scores, float* __restrict__ out) {
  __shared__ float diag[Bsz];
  __shared__ float wred[4];
  int t = threadIdx.x;
  diag[t] = scores[t * Bsz + t];
  __syncthreads();
  float di = diag[t];
  float mxs = 0.f, mxi = 0.f;
  for (int j = 0; j < Bsz; ++j) {
    if (j == t) continue;
    float srow = scores[t * Bsz + j];
    float scol = scores[j * Bsz + t];
    mxs = fmaxf(mxs, 0.2f + srow - di);
    mxi = fmaxf(mxi, 0.2f + scol - di);
  }
  float v = mxs + mxi;
  #pragma unroll
  for (int m = 32; m; m >>= 1) v += __shfl_xor(v, m);
  if ((t & 63) == 0) wred[t >> 6] = v;
  __syncthreads();
  if (t == 0) out[0] = wred[0] + wred[1] + wred[2] + wred[3];
}

extern "C" void kernel_launch(void* const* d_in, const int* in_sizes, int n_in,
                              void* d_out, int out_size, void* d_ws, size_t ws_size,
                              hipStream_t stream) {
  const float* im_set = (const float*)d_in[0];
  const float* s_seq  = (const float*)d_in[1];
  const int*   im_len = (const int*)d_in[2];
  const int*   s_len  = (const int*)d_in[3];
  float* out = (float*)d_out;

  unsigned short* im_bf = (unsigned short*)d_ws;                 // 256*36*1024*2 B
  unsigned short* s_bf  = im_bf + (size_t)Bsz * NIM * KD;        // 256*32*1024*2 B
  float* scores = (float*)(s_bf + (size_t)Bsz * NS * KD);        // 256*256*4 B

  stage_im<<<dim3(18, Bsz), 256, 0, stream>>>(im_set, im_len, im_bf);
  stage_s <<<dim3(16, Bsz), 256, 0, stream>>>(s_seq, s_len, s_bf);
  score_kernel<<<2048, 256, 0, stream>>>(im_bf, s_bf, scores);
  finalize_kernel<<<1, Bsz, 0, stream>>>(scores, out);
}